// Round 3
// baseline (291.786 us; speedup 1.0000x reference)
//
#include <hip/hip_runtime.h>
#include <hip/hip_bf16.h>

// TopoGraphLayer: B=1024, NJ=16, NW=2, NT=2, D=128, H=128
// Strategy: factorized edge layer-1 (per-node projections), MFMA bf16 16x16x32
// everywhere, runtime dtype probe (f32 vs bf16 device buffers; mask format).

using short8 = __attribute__((ext_vector_type(8))) short;
using f32x4  = __attribute__((ext_vector_type(4))) float;

#define DEVI __device__ __forceinline__

DEVI float b2f(short s){
  unsigned u = ((unsigned)(unsigned short)s) << 16;
  float f; __builtin_memcpy(&f, &u, 4); return f;
}
DEVI short f2b(float f){
  __hip_bfloat16 h = __float2bfloat16(f);
  short s; __builtin_memcpy(&s, &h, 2); return s;
}
DEVI float ldflex(const void* p, long i, int bf){
  return bf ? b2f(((const short*)p)[i]) : ((const float*)p)[i];
}
DEVI f32x4 mfma16(short8 a, short8 b, f32x4 c){
  return __builtin_amdgcn_mfma_f32_16x16x32_bf16(a, b, c, 0, 0, 0);
}

// ---------------- ws byte offsets (all 256-aligned) ----------------
// flags[16] ints | maskf f32[16384] | invcnt f32[1024] | XJ/XW/XT bf16 |
// W1T bf16[14][128][128] | W2T bf16[7][128][128] | biases f32 |
// JW1T bf16[128][512] | JW2T | WT weights | UV f32[14680064] | POOL bf16[7340032]
constexpr size_t OF_MASKF  = 256;
constexpr size_t OF_INVCNT = 65792;
constexpr size_t OF_XJ     = 69888;
constexpr size_t OF_XW     = 4264192;
constexpr size_t OF_XT     = 4788480;
constexpr size_t OF_W1T    = 5312768;
constexpr size_t OF_W2T    = 5771520;
constexpr size_t OF_EB1F   = 6000896;
constexpr size_t OF_EB2F   = 6004480;
constexpr size_t OF_JW1T   = 6008064;
constexpr size_t OF_JW2T   = 6139136;
constexpr size_t OF_JB1F   = 6171904;
constexpr size_t OF_JB2F   = 6172416;
constexpr size_t OF_WTW1T  = 6172928;
constexpr size_t OF_WTW2T  = 6369536;
constexpr size_t OF_WTB1F  = 6435072;
constexpr size_t OF_WTB2F  = 6436096;
constexpr size_t OF_UV     = 6437120;   // f32, 14,680,064 elems
constexpr size_t OF_POOL   = 65157376;  // bf16, 7,340,032 elems (end ~79.8MB)

// projection jobs: (tensor, net, half). job = net*2 + half. src half gets bias.
__constant__ long long PJ_OFF[14] = {0,2097152,4194304,6291456,6553600,8650752,
  8912896,9175040,11272192,11534336,11796480,12058624,14155776,14417920};
__constant__ int PJ_SRC[14] = {0,0,0,1,0,2,1,0,1,2,2,0,2,1}; // 0=J,1=W,2=T
__constant__ int PJ_CUM[15] = {0,128,256,384,400,528,544,560,688,704,720,736,864,880,896};
// edge nets
__constant__ int EN_CUM[8]  = {0,1024,1152,1280,1408,1424,1552,1568};
__constant__ int EN_LGNS[7] = {4,4,4,1,1,1,1};
__constant__ int EN_LGND[7] = {4,1,1,4,1,4,1};
__constant__ int EN_MSK[7]  = {1,0,0,1,0,1,0};
__constant__ long long EN_POOL[7] = {0,2097152,4194304,6291456,6553600,6815744,7077888};

// -------- probe: detect float dtype (f32 vs bf16) and mask format --------
__global__ __launch_bounds__(64) void k_probe(const void* jets, const void* mask, int* flags){
  if(threadIdx.x != 0) return;
  const unsigned short* u = (const unsigned short*)jets;
  int extreme = 0;
  for(int i=0;i<512;i+=2){ int e=(u[i]>>7)&0xff; if(e<110||e>140) extreme++; }
  flags[0] = (extreme <= 32) ? 1 : 0;  // 1=bf16, 0=f32
  const unsigned* mw = (const unsigned*)mask;
  bool all01=true, allf32=true;
  for(int i=0;i<256;i++){ unsigned w=mw[i]; if(w>1u) all01=false; if(w!=0u&&w!=0x3F800000u) allf32=false; }
  const unsigned short* mu=(const unsigned short*)mask;
  bool allbfv=true; int evnz=0;
  for(int i=0;i<512;i++){ unsigned short v=mu[i]; if(v!=0&&v!=0x3F80) allbfv=false; if((i&1)==0&&v!=0) evnz++; }
  const unsigned char* mb=(const unsigned char*)mask;
  bool allb01=true;
  for(int i=0;i<1024;i++){ if(mb[i]>1) allb01=false; }
  int fmt = 0;                   // 0=int32
  if(all01) fmt=0;
  else if(allbfv && evnz>0) fmt=2; // bf16
  else if(allf32) fmt=3;           // f32
  else if(allb01) fmt=1;           // u8
  flags[1] = fmt;
}

// -------- maskf + invcnt --------
__global__ __launch_bounds__(256) void k_mask(const void* mask, const int* flags,
                                              float* maskf, float* invcnt){
  int t = blockIdx.x*256 + threadIdx.x;  // 0..16383
  int fmt = flags[1];
  float m;
  if(fmt==0)      m = (((const int*)mask)[t]!=0) ? 1.f : 0.f;
  else if(fmt==1) m = (((const unsigned char*)mask)[t]!=0) ? 1.f : 0.f;
  else if(fmt==2) m = (b2f(((const short*)mask)[t])!=0.f) ? 1.f : 0.f;
  else            m = (((const float*)mask)[t]!=0.f) ? 1.f : 0.f;
  maskf[t] = m;
  float s = m;
  for(int o=1;o<16;o<<=1) s += __shfl_xor(s, o);
  if((t&15)==0) invcnt[t>>4] = 1.f / fmaxf(s, 1.f);
}

// -------- convert node inputs to canonical bf16 --------
__global__ __launch_bounds__(256) void k_convx(const void* jets, const void* nw, const void* nt,
                                               const int* flags, short* XJ, short* XW, short* XT){
  long i = (long)blockIdx.x*256 + threadIdx.x;
  int bf = flags[0];
  if(i < 2097152)      XJ[i]         = f2b(ldflex(jets, i, bf));
  else if(i < 2359296) XW[i-2097152] = f2b(ldflex(nw,   i-2097152, bf));
  else                 XT[i-2359296] = f2b(ldflex(nt,   i-2359296, bf));
}

// -------- convert + transpose all weights; biases to f32 --------
__global__ __launch_bounds__(256) void k_convw(
    const void* eW1, const void* eb1, const void* eW2, const void* eb2,
    const void* jW1, const void* jb1, const void* jW2, const void* jb2,
    const void* wW1, const void* wb1, const void* wW2, const void* wb2,
    const int* flags, short* W1T, short* W2T, float* EB1F, float* EB2F,
    short* JW1T, short* JW2T, float* JB1F, float* JB2F,
    short* WTW1T, short* WTW2T, float* WTB1F, float* WTB2F){
  long i = (long)blockIdx.x*256 + threadIdx.x;
  int bf = flags[0];
  if(i >= 559616) return;
  if(i < 229376){                    // W1T[job][nn][kk] = edge_W1[net][h*128+kk][nn]
    int job=(int)(i/16384), r=(int)(i%16384), nn=r/128, kk=r%128;
    int net=job>>1, h=job&1;
    W1T[i] = f2b(ldflex(eW1, (long)net*32768 + (long)(h*128+kk)*128 + nn, bf));
  } else if(i < 344064){             // W2T[n][nn][kk] = edge_W2[n][kk][nn]
    long id=i-229376; int n=(int)(id/16384), r=(int)(id%16384), nn=r/128, kk=r%128;
    W2T[id] = f2b(ldflex(eW2, (long)n*16384 + (long)kk*128 + nn, bf));
  } else if(i < 409600){             // JW1T[nn][kk<512] = jet_W1[kk][nn]
    long id=i-344064; int nn=(int)(id/512), kk=(int)(id%512);
    JW1T[id] = f2b(ldflex(jW1, (long)kk*128 + nn, bf));
  } else if(i < 425984){             // JW2T[nn][kk]
    long id=i-409600; int nn=(int)(id/128), kk=(int)(id%128);
    JW2T[id] = f2b(ldflex(jW2, (long)kk*128 + nn, bf));
  } else if(i < 524288){             // WTW1T[w][nn][kk<384]
    long id=i-425984; int wn=(int)(id/49152), r=(int)(id%49152), nn=r/384, kk=r%384;
    WTW1T[id] = f2b(ldflex(wW1, (long)wn*49152 + (long)kk*128 + nn, bf));
  } else if(i < 557056){             // WTW2T[w][nn][kk]
    long id=i-524288; int wn=(int)(id/16384), r=(int)(id%16384), nn=r/128, kk=r%128;
    WTW2T[id] = f2b(ldflex(wW2, (long)wn*16384 + (long)kk*128 + nn, bf));
  } else {                           // biases
    long id=i-557056;
    if(id<896)        EB1F[id]       = ldflex(eb1, id, bf);
    else if(id<1792)  EB2F[id-896]   = ldflex(eb2, id-896, bf);
    else if(id<1920)  JB1F[id-1792]  = ldflex(jb1, id-1792, bf);
    else if(id<2048)  JB2F[id-1920]  = ldflex(jb2, id-1920, bf);
    else if(id<2304)  WTB1F[id-2048] = ldflex(wb1, id-2048, bf);
    else              WTB2F[id-2304] = ldflex(wb2, id-2304, bf);
  }
}

// -------- projections: U/V[row][128] (f32) = X @ W1half (+b1 on src half) --------
__global__ __launch_bounds__(256) void k_proj(const short* XJ, const short* XW, const short* XT,
                                              const short* W1T, const float* EB1F, float* UV){
  int bid = blockIdx.x;
  int job = 0;
  while(bid >= PJ_CUM[job+1]) job++;
  long row0 = (long)(bid - PJ_CUM[job]) * 128;
  const short* X = (PJ_SRC[job]==0) ? XJ : ((PJ_SRC[job]==1) ? XW : XT);
  const short* W = W1T + (long)job*16384;
  float* out = UV + PJ_OFF[job];
  int net = job>>1; bool addb = (job&1)==0;
  int lane = threadIdx.x & 63, wv = threadIdx.x >> 6;
  int cl = lane & 15, kh = lane >> 4;
  f32x4 acc[2][8] = {};
  for(int k0=0;k0<128;k0+=32){
    short8 a[2], b[8];
    #pragma unroll
    for(int mt=0;mt<2;mt++)
      a[mt] = *(const short8*)(X + (row0 + wv*32 + mt*16 + cl)*128 + k0 + kh*8);
    #pragma unroll
    for(int nt=0;nt<8;nt++)
      b[nt] = *(const short8*)(W + (nt*16 + cl)*128 + k0 + kh*8);
    #pragma unroll
    for(int mt=0;mt<2;mt++)
      #pragma unroll
      for(int nt=0;nt<8;nt++)
        acc[mt][nt] = mfma16(a[mt], b[nt], acc[mt][nt]);
  }
  #pragma unroll
  for(int mt=0;mt<2;mt++)
    #pragma unroll
    for(int nt=0;nt<8;nt++){
      int col = nt*16 + cl;
      float bias = addb ? EB1F[net*128 + col] : 0.f;
      #pragma unroll
      for(int r=0;r<4;r++){
        long row = row0 + wv*32 + mt*16 + kh*4 + r;
        out[row*128 + col] = acc[mt][nt][r] + bias;
      }
    }
}

// -------- edge layer2 + pooling: per wg 256 edge rows of one net --------
__global__ __launch_bounds__(256) void k_edge(const float* UV, const short* W2T, const float* EB2F,
                                              const float* maskf, const float* invcnt, short* POOL){
  int bid = blockIdx.x;
  int net = 0;
  while(bid >= EN_CUM[net+1]) net++;
  int idx = bid - EN_CUM[net];
  int lgNs = EN_LGNS[net], lgNd = EN_LGND[net], masked = EN_MSK[net];
  int Ns = 1<<lgNs, Nd = 1<<lgNd;
  int lgG = 8 - lgNs - lgNd;
  long b0 = (long)idx << lgG;
  const float* U = UV + PJ_OFF[2*net];
  const float* V = UV + PJ_OFF[2*net+1];
  const short* W = W2T + (long)net*16384;
  short* pool = POOL + EN_POOL[net];
  int lane = threadIdx.x & 63, wv = threadIdx.x >> 6;
  int cl = lane & 15, kh = lane >> 4;
  f32x4 acc[4][8] = {};
  for(int k0=0;k0<128;k0+=32){
    short8 b[8];
    #pragma unroll
    for(int nt=0;nt<8;nt++)
      b[nt] = *(const short8*)(W + (nt*16 + cl)*128 + k0 + kh*8);
    short8 a[4];
    #pragma unroll
    for(int mt=0;mt<4;mt++){
      int rwg = wv*64 + mt*16 + cl;
      long urow = b0*Ns + (rwg >> lgNd);
      long vrow = b0*Nd + (((rwg >> (lgNs+lgNd)) << lgNd) | (rwg & (Nd-1)));
      f32x4 u0 = *(const f32x4*)(U + urow*128 + k0 + kh*8);
      f32x4 u1 = *(const f32x4*)(U + urow*128 + k0 + kh*8 + 4);
      f32x4 v0 = *(const f32x4*)(V + vrow*128 + k0 + kh*8);
      f32x4 v1 = *(const f32x4*)(V + vrow*128 + k0 + kh*8 + 4);
      #pragma unroll
      for(int e=0;e<4;e++) a[mt][e]   = f2b(fmaxf(u0[e]+v0[e], 0.f));
      #pragma unroll
      for(int e=0;e<4;e++) a[mt][4+e] = f2b(fmaxf(u1[e]+v1[e], 0.f));
    }
    #pragma unroll
    for(int mt=0;mt<4;mt++)
      #pragma unroll
      for(int nt=0;nt<8;nt++)
        acc[mt][nt] = mfma16(a[mt], b[nt], acc[mt][nt]);
  }
  #pragma unroll
  for(int mt=0;mt<4;mt++){
    float wr[4];
    if(masked){
      #pragma unroll
      for(int r=0;r<4;r++){
        int rwg = wv*64 + mt*16 + kh*4 + r;
        long bb = b0 + (rwg >> (lgNs+4));
        wr[r] = maskf[bb*16 + (rwg & 15)] * invcnt[bb];
      }
    }
    #pragma unroll
    for(int nt=0;nt<8;nt++){
      int col = nt*16 + cl;
      float bias = EB2F[net*128 + col];
      float v0 = fmaxf(acc[mt][nt][0]+bias, 0.f);
      float v1 = fmaxf(acc[mt][nt][1]+bias, 0.f);
      float v2 = fmaxf(acc[mt][nt][2]+bias, 0.f);
      float v3 = fmaxf(acc[mt][nt][3]+bias, 0.f);
      if(masked){
        float s = v0*wr[0] + v1*wr[1] + v2*wr[2] + v3*wr[3];
        s += __shfl_xor(s, 16);
        s += __shfl_xor(s, 32);
        if(lane < 16){
          long prow = b0*Ns + (wv*4 + mt);
          pool[prow*128 + col] = f2b(s);
        }
      } else {
        int P = wv*32 + mt*8 + kh*2;
        long pr = b0*Ns + P;
        pool[pr*128 + col]     = f2b((v0+v1)*0.5f);
        pool[(pr+1)*128 + col] = f2b((v2+v3)*0.5f);
      }
    }
  }
}

// -------- node nets: gathered concat -> MLP2 -> (mask) -> out --------
__global__ __launch_bounds__(256) void k_node(const short* XJ, const short* XW, const short* XT,
    const short* POOL, const short* JW1T, const short* JW2T, const float* JB1F, const float* JB2F,
    const short* WTW1T, const short* WTW2T, const float* WTB1F, const float* WTB2F,
    const float* maskf, const int* flags, void* out){
  __shared__ short hs[16384];  // 128x128 bf16, XOR-swizzled
  int bid = blockIdx.x;
  int net; long row0;
  if(bid < 128){ net=0; row0=(long)bid*128; }
  else if(bid < 144){ net=1; row0=(long)(bid-128)*128; }
  else { net=2; row0=(long)(bid-144)*128; }
  int K1 = (net==0) ? 512 : 384;
  const short* X = (net==0) ? XJ : ((net==1) ? XW : XT);
  const short *PA, *PB, *PC = nullptr;
  if(net==0){ PA=POOL; PB=POOL+2097152; PC=POOL+4194304; }
  else if(net==1){ PA=POOL+6291456; PB=POOL+6553600; }
  else { PA=POOL+6815744; PB=POOL+7077888; }
  const short* W1 = (net==0) ? JW1T : WTW1T + (long)(net-1)*49152;
  const short* W2 = (net==0) ? JW2T : WTW2T + (long)(net-1)*16384;
  const float* B1 = (net==0) ? JB1F : WTB1F + (net-1)*128;
  const float* B2 = (net==0) ? JB2F : WTB2F + (net-1)*128;
  int lane = threadIdx.x & 63, wv = threadIdx.x >> 6;
  int cl = lane & 15, kh = lane >> 4;
  f32x4 acc[2][8] = {};
  for(int ks=0; ks<K1/32; ks++){
    int k0 = ks*32;
    int kk = k0 + kh*8;
    int sel = kk >> 7, ko = kk & 127;     // wave-uniform (32-blocks don't straddle 128)
    const short* SA = (sel==0) ? X : ((sel==1) ? PA : ((sel==2) ? PB : PC));
    short8 a[2], b[8];
    #pragma unroll
    for(int mt=0;mt<2;mt++){
      long row = row0 + wv*32 + mt*16 + cl;
      a[mt] = *(const short8*)(SA + row*128 + ko);
    }
    #pragma unroll
    for(int nt=0;nt<8;nt++)
      b[nt] = *(const short8*)(W1 + (long)(nt*16 + cl)*K1 + kk);
    #pragma unroll
    for(int mt=0;mt<2;mt++)
      #pragma unroll
      for(int nt=0;nt<8;nt++)
        acc[mt][nt] = mfma16(a[mt], b[nt], acc[mt][nt]);
  }
  #pragma unroll
  for(int mt=0;mt<2;mt++)
    #pragma unroll
    for(int nt=0;nt<8;nt++){
      int col = nt*16 + cl;
      float bias = B1[col];
      #pragma unroll
      for(int r=0;r<4;r++){
        int rl = wv*32 + mt*16 + kh*4 + r;
        float v = fmaxf(acc[mt][nt][r] + bias, 0.f);
        hs[(rl*128 + col) ^ ((rl&7)<<3)] = f2b(v);
      }
    }
  __syncthreads();
  f32x4 acc2[2][8] = {};
  for(int k0=0;k0<128;k0+=32){
    short8 a[2], b[8];
    #pragma unroll
    for(int mt=0;mt<2;mt++){
      int rl = wv*32 + mt*16 + cl;
      int idx = (rl*128 + k0 + kh*8) ^ ((rl&7)<<3);
      a[mt] = *(const short8*)(&hs[idx]);
    }
    #pragma unroll
    for(int nt=0;nt<8;nt++)
      b[nt] = *(const short8*)(W2 + (nt*16 + cl)*128 + k0 + kh*8);
    #pragma unroll
    for(int mt=0;mt<2;mt++)
      #pragma unroll
      for(int nt=0;nt<8;nt++)
        acc2[mt][nt] = mfma16(a[mt], b[nt], acc2[mt][nt]);
  }
  int obf = flags[0];
  #pragma unroll
  for(int mt=0;mt<2;mt++)
    #pragma unroll
    for(int nt=0;nt<8;nt++){
      int col = nt*16 + cl;
      float bias = B2[col];
      #pragma unroll
      for(int r=0;r<4;r++){
        int rl = wv*32 + mt*16 + kh*4 + r;
        long grow = row0 + rl;
        float v = fmaxf(acc2[mt][nt][r] + bias, 0.f);
        long bb, node;
        if(net==0){ bb = grow>>4; node = grow&15; v *= maskf[grow]; }
        else if(net==1){ bb = grow>>1; node = 16 + (grow&1); }
        else { bb = grow>>1; node = 18 + (grow&1); }
        long oi = (bb*20 + node)*128 + col;
        if(obf) ((__hip_bfloat16*)out)[oi] = __float2bfloat16(v);
        else    ((float*)out)[oi] = v;
      }
    }
}

extern "C" void kernel_launch(void* const* d_in, const int* in_sizes, int n_in,
                              void* d_out, int out_size, void* d_ws, size_t ws_size,
                              hipStream_t stream){
  char* ws = (char*)d_ws;
  int*   flags  = (int*)ws;
  float* maskf  = (float*)(ws + OF_MASKF);
  float* invcnt = (float*)(ws + OF_INVCNT);
  short* XJ     = (short*)(ws + OF_XJ);
  short* XW     = (short*)(ws + OF_XW);
  short* XT     = (short*)(ws + OF_XT);
  short* W1T    = (short*)(ws + OF_W1T);
  short* W2T    = (short*)(ws + OF_W2T);
  float* EB1F   = (float*)(ws + OF_EB1F);
  float* EB2F   = (float*)(ws + OF_EB2F);
  short* JW1T   = (short*)(ws + OF_JW1T);
  short* JW2T   = (short*)(ws + OF_JW2T);
  float* JB1F   = (float*)(ws + OF_JB1F);
  float* JB2F   = (float*)(ws + OF_JB2F);
  short* WTW1T  = (short*)(ws + OF_WTW1T);
  short* WTW2T  = (short*)(ws + OF_WTW2T);
  float* WTB1F  = (float*)(ws + OF_WTB1F);
  float* WTB2F  = (float*)(ws + OF_WTB2F);
  float* UV     = (float*)(ws + OF_UV);
  short* POOL   = (short*)(ws + OF_POOL);

  k_probe<<<1, 64, 0, stream>>>(d_in[0], d_in[3], flags);
  k_mask <<<64, 256, 0, stream>>>(d_in[3], flags, maskf, invcnt);
  k_convx<<<10240, 256, 0, stream>>>(d_in[0], d_in[1], d_in[2], flags, XJ, XW, XT);
  k_convw<<<2186, 256, 0, stream>>>(d_in[4], d_in[5], d_in[6], d_in[7],
                                    d_in[8], d_in[9], d_in[10], d_in[11],
                                    d_in[12], d_in[13], d_in[14], d_in[15],
                                    flags, W1T, W2T, EB1F, EB2F, JW1T, JW2T, JB1F, JB2F,
                                    WTW1T, WTW2T, WTB1F, WTB2F);
  k_proj <<<896, 256, 0, stream>>>(XJ, XW, XT, W1T, EB1F, UV);
  k_edge <<<1568, 256, 0, stream>>>(UV, W2T, EB2F, maskf, invcnt, POOL);
  k_node <<<160, 256, 0, stream>>>(XJ, XW, XT, POOL, JW1T, JW2T, JB1F, JB2F,
                                   WTW1T, WTW2T, WTB1F, WTB2F, maskf, flags, d_out);
}

// Round 4
// 203.656 us; speedup vs baseline: 1.4327x; 1.4327x over previous
//
#include <hip/hip_runtime.h>
#include <hip/hip_bf16.h>

// TopoGraphLayer: B=1024, NJ=16, NW=2, NT=2, D=128, H=128
// R3 redesign: LDS-staged operands + reduced per-wave accumulator state.
// k_edge was 117.8us: latency-serialized (128 acc VGPRs -> ~1 wave/SIMD, 96
// exposed VMEM loads/wave). Now: A=relu(U+V) built in LDS (coalesced, swizzled),
// VMEM-free MFMA loop, acc[2][8]=64 regs, 128 rows/wg.

using short4v = __attribute__((ext_vector_type(4))) short;
using short8 = __attribute__((ext_vector_type(8))) short;
using f32x4  = __attribute__((ext_vector_type(4))) float;

#define DEVI __device__ __forceinline__

DEVI float b2f(short s){
  unsigned u = ((unsigned)(unsigned short)s) << 16;
  float f; __builtin_memcpy(&f, &u, 4); return f;
}
DEVI short f2b(float f){
  __hip_bfloat16 h = __float2bfloat16(f);
  short s; __builtin_memcpy(&s, &h, 2); return s;
}
DEVI float ldflex(const void* p, long i, int bf){
  return bf ? b2f(((const short*)p)[i]) : ((const float*)p)[i];
}
DEVI f32x4 mfma16(short8 a, short8 b, f32x4 c){
  return __builtin_amdgcn_mfma_f32_16x16x32_bf16(a, b, c, 0, 0, 0);
}

// ---------------- ws byte offsets (all 256-aligned) ----------------
constexpr size_t OF_MASKF  = 256;
constexpr size_t OF_INVCNT = 65792;
constexpr size_t OF_XJ     = 69888;
constexpr size_t OF_XW     = 4264192;
constexpr size_t OF_XT     = 4788480;
constexpr size_t OF_W1T    = 5312768;   // bf16 [7][128][256]
constexpr size_t OF_W2T    = 5771520;   // bf16 [7][128][128]
constexpr size_t OF_EB1F   = 6000896;
constexpr size_t OF_EB2F   = 6004480;
constexpr size_t OF_JW1T   = 6008064;   // bf16 [128][512]
constexpr size_t OF_JW2T   = 6139136;   // bf16 [128][128]
constexpr size_t OF_JB1F   = 6171904;
constexpr size_t OF_JB2F   = 6172416;
constexpr size_t OF_WTW1T  = 6172928;   // bf16 [2][128][384]
constexpr size_t OF_WTW2T  = 6369536;   // bf16 [2][128][128]
constexpr size_t OF_WTB1F  = 6435072;
constexpr size_t OF_WTB2F  = 6436096;
constexpr size_t OF_UV     = 6437120;   // f32, 14,680,064 elems
constexpr size_t OF_POOL   = 65157376;  // bf16, 7,340,032 elems (end ~79.8MB)

// projection jobs: job = net*2 + half (half0=src gets bias). 128 rows/wg.
__constant__ long long PJ_OFF[14] = {0,2097152,4194304,6291456,6553600,8650752,
  8912896,9175040,11272192,11534336,11796480,12058624,14155776,14417920};
__constant__ int PJ_SRC[14] = {0,0,0,1,0,2,1,0,1,2,2,0,2,1}; // 0=J,1=W,2=T
__constant__ int PJ_CUM[15] = {0,128,256,384,400,528,544,560,688,704,720,736,864,880,896};
// edge nets, 128 edge-rows per wg
__constant__ int EN_CUM[8]  = {0,2048,2304,2560,2816,2848,3104,3136};
__constant__ int EN_LGNS[7] = {4,4,4,1,1,1,1};
__constant__ int EN_LGND[7] = {4,1,1,4,1,4,1};
__constant__ long long EN_POOL[7] = {0,2097152,4194304,6291456,6553600,6815744,7077888};
// transpose jobs (dst col-major mats, all C=128 source cols)
__constant__ int TJ_CUM[21] = {0,32,64,96,128,160,192,224,240,256,272,288,304,320,336,400,416,464,512,528,544};
__constant__ int TJ_SEL[20] = {0,0,0,0,0,0,0,1,1,1,1,1,1,1,2,3,4,4,5,5};
__constant__ int TJ_OFF[20] = {0,32768,65536,98304,131072,163840,196608,
                               0,16384,32768,49152,65536,81920,98304,
                               0,0,0,49152,0,16384};
__constant__ int TJ_R[20]   = {256,256,256,256,256,256,256,128,128,128,128,128,128,128,512,128,384,384,128,128};

// -------- probe: detect float dtype (f32 vs bf16) and mask format --------
__global__ __launch_bounds__(64) void k_probe(const void* jets, const void* mask, int* flags){
  int l = threadIdx.x;
  int extreme = 0;
  #pragma unroll
  for(int s=0;s<4;s++){
    unsigned short v = ((const unsigned short*)jets)[(l*4+s)*2];
    int e = (v>>7)&0xff;
    if(e<110||e>140) extreme++;
  }
  #pragma unroll
  for(int o=1;o<64;o<<=1) extreme += __shfl_xor(extreme, o);
  bool all01=true, allf32=true;
  #pragma unroll
  for(int s=0;s<4;s++){
    unsigned w = ((const unsigned*)mask)[l*4+s];
    if(w>1u) all01=false;
    if(w!=0u && w!=0x3F800000u) allf32=false;
  }
  bool allbfv=true; int evnz=0;
  #pragma unroll
  for(int s=0;s<8;s++){
    unsigned short v = ((const unsigned short*)mask)[l*8+s];
    if(v!=0&&v!=0x3F80) allbfv=false;
    if(((l*8+s)&1)==0 && v!=0) evnz++;
  }
  #pragma unroll
  for(int o=1;o<64;o<<=1) evnz += __shfl_xor(evnz, o);
  bool allb01=true;
  #pragma unroll
  for(int s=0;s<16;s++){ if(((const unsigned char*)mask)[l*16+s]>1) allb01=false; }
  int a01 = __all(all01), af32 = __all(allf32), abf = __all(allbfv), ab01 = __all(allb01);
  if(l==0){
    flags[0] = (extreme <= 32) ? 1 : 0;   // 1=bf16 inputs, 0=f32
    int fmt = 0;
    if(a01) fmt=0; else if(abf && evnz>0) fmt=2; else if(af32) fmt=3; else if(ab01) fmt=1;
    flags[1] = fmt;
  }
}

// -------- maskf + invcnt --------
__global__ __launch_bounds__(256) void k_mask(const void* mask, const int* flags,
                                              float* maskf, float* invcnt){
  int t = blockIdx.x*256 + threadIdx.x;  // 0..16383
  int fmt = flags[1];
  float m;
  if(fmt==0)      m = (((const int*)mask)[t]!=0) ? 1.f : 0.f;
  else if(fmt==1) m = (((const unsigned char*)mask)[t]!=0) ? 1.f : 0.f;
  else if(fmt==2) m = (b2f(((const short*)mask)[t])!=0.f) ? 1.f : 0.f;
  else            m = (((const float*)mask)[t]!=0.f) ? 1.f : 0.f;
  maskf[t] = m;
  float s = m;
  for(int o=1;o<16;o<<=1) s += __shfl_xor(s, o);
  if((t&15)==0) invcnt[t>>4] = 1.f / fmaxf(s, 1.f);
}

// -------- biases to f32 --------
__global__ __launch_bounds__(256) void k_bias(const void* eb1, const void* eb2, const void* jb1,
    const void* jb2, const void* wb1, const void* wb2, const int* flags,
    float* EB1F, float* EB2F, float* JB1F, float* JB2F, float* WTB1F, float* WTB2F){
  int id = blockIdx.x*256 + threadIdx.x;
  int bf = flags[0];
  if(id<896)        EB1F[id]       = ldflex(eb1, id, bf);
  else if(id<1792)  EB2F[id-896]   = ldflex(eb2, id-896, bf);
  else if(id<1920)  JB1F[id-1792]  = ldflex(jb1, id-1792, bf);
  else if(id<2048)  JB2F[id-1920]  = ldflex(jb2, id-1920, bf);
  else if(id<2304)  WTB1F[id-2048] = ldflex(wb1, id-2048, bf);
  else if(id<2560)  WTB2F[id-2304] = ldflex(wb2, id-2304, bf);
}

// -------- convert node inputs to canonical bf16 (x4 vectorized) --------
__global__ __launch_bounds__(256) void k_convx(const void* jets, const void* nw, const void* nt,
                                               const int* flags, short* XJ, short* XW, short* XT){
  long i = ((long)blockIdx.x*256 + threadIdx.x)*4;
  int bf = flags[0];
  const void* src; short* dst; long o;
  if(i < 2097152){ src=jets; dst=XJ; o=i; }
  else if(i < 2359296){ src=nw; dst=XW; o=i-2097152; }
  else { src=nt; dst=XT; o=i-2359296; }
  short4v r;
  if(bf){
    r = *(const short4v*)((const short*)src + o);
  } else {
    f32x4 v = *(const f32x4*)((const float*)src + o);
    #pragma unroll
    for(int e=0;e<4;e++) r[e] = f2b(v[e]);
  }
  *(short4v*)(dst + o) = r;
}

// -------- weight transpose via LDS 32x32 tiles (src [R][128] -> dst [128][R]) --------
__global__ __launch_bounds__(256) void k_trans(const void* eW1, const void* eW2, const void* jW1,
    const void* jW2, const void* wW1, const void* wW2, const int* flags,
    short* W1T, short* W2T, short* JW1T, short* JW2T, short* WTW1T, short* WTW2T){
  __shared__ float tl[32][33];
  int tile = blockIdx.x; int job = 0;
  while(tile >= TJ_CUM[job+1]) job++;
  tile -= TJ_CUM[job];
  int sel = TJ_SEL[job]; long off = TJ_OFF[job]; int R = TJ_R[job];
  int bf = flags[0];
  const void* src = sel==0?eW1: sel==1?eW2: sel==2?jW1: sel==3?jW2: sel==4?wW1: wW2;
  short* dst = sel==0?W1T: sel==1?W2T: sel==2?JW1T: sel==3?JW2T: sel==4?WTW1T: WTW2T;
  int tr = (tile>>2)*32, tc = (tile&3)*32;
  int t = threadIdx.x, r = t>>3, c4 = (t&7)*4;
  #pragma unroll
  for(int j=0;j<4;j++) tl[r][c4+j] = ldflex(src, off + (long)(tr+r)*128 + tc + c4 + j, bf);
  __syncthreads();
  short4v o;
  #pragma unroll
  for(int j=0;j<4;j++) o[j] = f2b(tl[c4+j][r]);
  *(short4v*)(dst + off + (long)(tc+r)*R + tr + c4) = o;
}

// -------- projections: UV[row][128] f32 = X @ W1half (+b1 on src half) --------
// 128 rows/wg; X tile staged in LDS (swizzled); VMEM-free a-reads.
__global__ __launch_bounds__(256) void k_proj(const short* XJ, const short* XW, const short* XT,
                                              const short* W1T, const float* EB1F, float* UV){
  __shared__ short Xs[16384];
  int bid = blockIdx.x;
  int job = 0;
  while(bid >= PJ_CUM[job+1]) job++;
  long row0 = (long)(bid - PJ_CUM[job]) * 128;
  const short* X = (PJ_SRC[job]==0) ? XJ : ((PJ_SRC[job]==1) ? XW : XT);
  const short* W = W1T + (long)(job>>1)*32768 + (job&1)*128;  // rows stride 256
  float* out = UV + PJ_OFF[job];
  int net = job>>1; bool addb = (job&1)==0;
  int t = threadIdx.x;
  #pragma unroll
  for(int j=0;j<8;j++){
    int o = j*4096 + t*16;
    int row = o >> 8, rem = o & 255;
    short8 v = *(const short8*)(X + (row0+row)*128 + (rem>>1));
    *(short8*)((char*)Xs + ((row*256 + rem) ^ ((row&7)<<4))) = v;
  }
  __syncthreads();
  int lane = t & 63, wv = t >> 6;
  int cl = lane & 15, kh = lane >> 4;
  f32x4 acc[2][8] = {};
  for(int k0=0;k0<128;k0+=32){
    short8 a[2], b[8];
    #pragma unroll
    for(int mt=0;mt<2;mt++){
      int rr = wv*32 + mt*16 + cl;
      a[mt] = *(const short8*)((const char*)Xs + ((rr*256 + (k0 + kh*8)*2) ^ ((rr&7)<<4)));
    }
    #pragma unroll
    for(int nt=0;nt<8;nt++)
      b[nt] = *(const short8*)(W + (nt*16 + cl)*256 + k0 + kh*8);
    #pragma unroll
    for(int mt=0;mt<2;mt++)
      #pragma unroll
      for(int nt=0;nt<8;nt++)
        acc[mt][nt] = mfma16(a[mt], b[nt], acc[mt][nt]);
  }
  #pragma unroll
  for(int mt=0;mt<2;mt++)
    #pragma unroll
    for(int nt=0;nt<8;nt++){
      int col = nt*16 + cl;
      float bias = addb ? EB1F[net*128 + col] : 0.f;
      #pragma unroll
      for(int r=0;r<4;r++){
        long row = row0 + wv*32 + mt*16 + kh*4 + r;
        out[row*128 + col] = acc[mt][nt][r] + bias;
      }
    }
}

// -------- edge layer2 + pooling: 128 edge rows/wg, A=relu(U+V) built in LDS --------
__global__ __launch_bounds__(256) void k_edge(const float* UV, const short* W2T, const float* EB2F,
                                              const float* maskf, const float* invcnt, short* POOL){
  __shared__ short As[16384];  // 128 x 128 bf16, XOR-swizzled
  int bid = blockIdx.x;
  int net = 0;
  while(bid >= EN_CUM[net+1]) net++;
  int idx = bid - EN_CUM[net];
  int lgNs = EN_LGNS[net], lgNd = EN_LGND[net];
  int masked = (lgNd == 4);     // all masked nets pool over 16 jets
  long R0 = (long)idx * 128;
  const float* U = UV + PJ_OFF[2*net];
  const float* V = UV + PJ_OFF[2*net+1];
  const short* W = W2T + (long)net*16384;
  short* pool = POOL + EN_POOL[net];
  int t = threadIdx.x;
  {  // A build: thread t -> row t>>1, col half (t&1)*64
    int r = t >> 1, half = t & 1;
    long R = R0 + r;
    long urow = R >> lgNd;
    long vrow = ((R >> (lgNs+lgNd)) << lgNd) | (R & ((1<<lgNd)-1));
    const float* up = U + urow*128 + half*64;
    const float* vp = V + vrow*128 + half*64;
    int base = r*256 + half*128;
    int swz = (r&7)<<4;
    #pragma unroll
    for(int i=0;i<8;i++){
      f32x4 u0 = *(const f32x4*)(up + i*8);
      f32x4 u1 = *(const f32x4*)(up + i*8 + 4);
      f32x4 v0 = *(const f32x4*)(vp + i*8);
      f32x4 v1 = *(const f32x4*)(vp + i*8 + 4);
      short8 o;
      #pragma unroll
      for(int e=0;e<4;e++){
        o[e]   = f2b(fmaxf(u0[e]+v0[e], 0.f));
        o[4+e] = f2b(fmaxf(u1[e]+v1[e], 0.f));
      }
      *(short8*)((char*)As + ((base + i*16) ^ swz)) = o;
    }
  }
  __syncthreads();
  int lane = t & 63, wv = t >> 6;
  int cl = lane & 15, kh = lane >> 4;
  f32x4 acc[2][8] = {};
  for(int k0=0;k0<128;k0+=32){
    short8 a[2], b[8];
    #pragma unroll
    for(int mt=0;mt<2;mt++){
      int rr = wv*32 + mt*16 + cl;
      a[mt] = *(const short8*)((const char*)As + ((rr*256 + (k0 + kh*8)*2) ^ ((rr&7)<<4)));
    }
    #pragma unroll
    for(int nt=0;nt<8;nt++)
      b[nt] = *(const short8*)(W + (nt*16 + cl)*128 + k0 + kh*8);
    #pragma unroll
    for(int mt=0;mt<2;mt++)
      #pragma unroll
      for(int nt=0;nt<8;nt++)
        acc[mt][nt] = mfma16(a[mt], b[nt], acc[mt][nt]);
  }
  #pragma unroll
  for(int mt=0;mt<2;mt++){
    float wr[4];
    if(masked){
      #pragma unroll
      for(int r=0;r<4;r++){
        long R = R0 + wv*32 + mt*16 + kh*4 + r;
        long bb = R >> (lgNs+4);
        wr[r] = maskf[bb*16 + (R & 15)] * invcnt[bb];
      }
    }
    #pragma unroll
    for(int nt=0;nt<8;nt++){
      int col = nt*16 + cl;
      float bias = EB2F[net*128 + col];
      float v0 = fmaxf(acc[mt][nt][0]+bias, 0.f);
      float v1 = fmaxf(acc[mt][nt][1]+bias, 0.f);
      float v2 = fmaxf(acc[mt][nt][2]+bias, 0.f);
      float v3 = fmaxf(acc[mt][nt][3]+bias, 0.f);
      if(masked){
        float s = v0*wr[0] + v1*wr[1] + v2*wr[2] + v3*wr[3];
        s += __shfl_xor(s, 16);
        s += __shfl_xor(s, 32);
        if(lane < 16){
          long g = (R0 + wv*32 + mt*16) >> 4;
          pool[g*128 + col] = f2b(s);
        }
      } else {
        long g = (R0 + wv*32 + mt*16 + kh*4) >> 1;
        pool[g*128 + col]     = f2b((v0+v1)*0.5f);
        pool[(g+1)*128 + col] = f2b((v2+v3)*0.5f);
      }
    }
  }
}

// -------- node nets: 64 rows/wg (4 waves x 16 rows), h1 in LDS --------
__global__ __launch_bounds__(256) void k_node(const short* XJ, const short* XW, const short* XT,
    const short* POOL, const short* JW1T, const short* JW2T, const float* JB1F, const float* JB2F,
    const short* WTW1T, const short* WTW2T, const float* WTB1F, const float* WTB2F,
    const float* maskf, const int* flags, void* out){
  __shared__ short hs[8192];  // 64 x 128 bf16, XOR-swizzled
  int bid = blockIdx.x;
  int net; long row0;
  if(bid < 256){ net=0; row0=(long)bid*64; }
  else if(bid < 288){ net=1; row0=(long)(bid-256)*64; }
  else { net=2; row0=(long)(bid-288)*64; }
  int K1 = (net==0) ? 512 : 384;
  const short* X = (net==0) ? XJ : ((net==1) ? XW : XT);
  const short *PA, *PB, *PC = nullptr;
  if(net==0){ PA=POOL; PB=POOL+2097152; PC=POOL+4194304; }
  else if(net==1){ PA=POOL+6291456; PB=POOL+6553600; }
  else { PA=POOL+6815744; PB=POOL+7077888; }
  const short* W1 = (net==0) ? JW1T : WTW1T + (long)(net-1)*49152;
  const short* W2 = (net==0) ? JW2T : WTW2T + (long)(net-1)*16384;
  const float* B1 = (net==0) ? JB1F : WTB1F + (net-1)*128;
  const float* B2 = (net==0) ? JB2F : WTB2F + (net-1)*128;
  int t = threadIdx.x;
  int lane = t & 63, wv = t >> 6;
  int cl = lane & 15, kh = lane >> 4;
  f32x4 acc[8] = {};
  for(int ks=0; ks<K1/32; ks++){
    int kk = ks*32 + kh*8;
    int sel = kk >> 7, ko = kk & 127;   // wave-uniform per ks
    const short* SA = (sel==0) ? X : ((sel==1) ? PA : ((sel==2) ? PB : PC));
    short8 a = *(const short8*)(SA + (row0 + wv*16 + cl)*128 + ko);
    short8 b[8];
    #pragma unroll
    for(int nt=0;nt<8;nt++)
      b[nt] = *(const short8*)(W1 + (long)(nt*16 + cl)*K1 + ks*32 + kh*8);
    #pragma unroll
    for(int nt=0;nt<8;nt++)
      acc[nt] = mfma16(a, b[nt], acc[nt]);
  }
  #pragma unroll
  for(int nt=0;nt<8;nt++){
    int col = nt*16 + cl;
    float bias = B1[col];
    #pragma unroll
    for(int r=0;r<4;r++){
      int rl = wv*16 + kh*4 + r;
      float v = fmaxf(acc[nt][r] + bias, 0.f);
      *(short*)((char*)hs + ((rl*256 + col*2) ^ ((rl&7)<<4))) = f2b(v);
    }
  }
  __syncthreads();
  f32x4 acc2[8] = {};
  for(int k0=0;k0<128;k0+=32){
    int rr = wv*16 + cl;
    short8 a = *(const short8*)((const char*)hs + ((rr*256 + (k0 + kh*8)*2) ^ ((rr&7)<<4)));
    short8 b[8];
    #pragma unroll
    for(int nt=0;nt<8;nt++)
      b[nt] = *(const short8*)(W2 + (nt*16 + cl)*128 + k0 + kh*8);
    #pragma unroll
    for(int nt=0;nt<8;nt++)
      acc2[nt] = mfma16(a, b[nt], acc2[nt]);
  }
  int obf = flags[0];
  #pragma unroll
  for(int nt=0;nt<8;nt++){
    int col = nt*16 + cl;
    float bias = B2[col];
    #pragma unroll
    for(int r=0;r<4;r++){
      int rl = wv*16 + kh*4 + r;
      long grow = row0 + rl;
      float v = fmaxf(acc2[nt][r] + bias, 0.f);
      long bb, node;
      if(net==0){ bb = grow>>4; node = grow&15; v *= maskf[grow]; }
      else if(net==1){ bb = grow>>1; node = 16 + (grow&1); }
      else { bb = grow>>1; node = 18 + (grow&1); }
      long oi = (bb*20 + node)*128 + col;
      if(obf) ((__hip_bfloat16*)out)[oi] = __float2bfloat16(v);
      else    ((float*)out)[oi] = v;
    }
  }
}

extern "C" void kernel_launch(void* const* d_in, const int* in_sizes, int n_in,
                              void* d_out, int out_size, void* d_ws, size_t ws_size,
                              hipStream_t stream){
  char* ws = (char*)d_ws;
  int*   flags  = (int*)ws;
  float* maskf  = (float*)(ws + OF_MASKF);
  float* invcnt = (float*)(ws + OF_INVCNT);
  short* XJ     = (short*)(ws + OF_XJ);
  short* XW     = (short*)(ws + OF_XW);
  short* XT     = (short*)(ws + OF_XT);
  short* W1T    = (short*)(ws + OF_W1T);
  short* W2T    = (short*)(ws + OF_W2T);
  float* EB1F   = (float*)(ws + OF_EB1F);
  float* EB2F   = (float*)(ws + OF_EB2F);
  short* JW1T   = (short*)(ws + OF_JW1T);
  short* JW2T   = (short*)(ws + OF_JW2T);
  float* JB1F   = (float*)(ws + OF_JB1F);
  float* JB2F   = (float*)(ws + OF_JB2F);
  short* WTW1T  = (short*)(ws + OF_WTW1T);
  short* WTW2T  = (short*)(ws + OF_WTW2T);
  float* WTB1F  = (float*)(ws + OF_WTB1F);
  float* WTB2F  = (float*)(ws + OF_WTB2F);
  float* UV     = (float*)(ws + OF_UV);
  short* POOL   = (short*)(ws + OF_POOL);

  k_probe<<<1, 64, 0, stream>>>(d_in[0], d_in[3], flags);
  k_mask <<<64, 256, 0, stream>>>(d_in[3], flags, maskf, invcnt);
  k_bias <<<10, 256, 0, stream>>>(d_in[5], d_in[7], d_in[9], d_in[11], d_in[13], d_in[15],
                                  flags, EB1F, EB2F, JB1F, JB2F, WTB1F, WTB2F);
  k_convx<<<2560, 256, 0, stream>>>(d_in[0], d_in[1], d_in[2], flags, XJ, XW, XT);
  k_trans<<<544, 256, 0, stream>>>(d_in[4], d_in[6], d_in[8], d_in[10], d_in[12], d_in[14],
                                   flags, W1T, W2T, JW1T, JW2T, WTW1T, WTW2T);
  k_proj <<<896, 256, 0, stream>>>(XJ, XW, XT, W1T, EB1F, UV);
  k_edge <<<3136, 256, 0, stream>>>(UV, W2T, EB2F, maskf, invcnt, POOL);
  k_node <<<320, 256, 0, stream>>>(XJ, XW, XT, POOL, JW1T, JW2T, JB1F, JB2F,
                                   WTW1T, WTW2T, WTB1F, WTB2F, maskf, flags, d_out);
}

// Round 5
// 143.143 us; speedup vs baseline: 2.0384x; 1.4227x over previous
//
#include <hip/hip_runtime.h>
#include <hip/hip_bf16.h>

// TopoGraphLayer: B=1024, NJ=16, NW=2, NT=2, D=128, H=128
// R5: k_edge/k_proj rebuilt barrier-free + weight-frags-in-registers.
// R4 post-mortem: k_edge 113us was ~80% VMEM-latency wait (MfmaUtil 4.5%,
// VALU 15%, HBM 5%). Now: no LDS, no syncthreads, B-frags hoisted to regs,
// 8-chunk inner loop the compiler can software-pipeline; UV stored bf16.

using short4v = __attribute__((ext_vector_type(4))) short;
using short8 = __attribute__((ext_vector_type(8))) short;
using f32x4  = __attribute__((ext_vector_type(4))) float;

#define DEVI __device__ __forceinline__

DEVI float b2f(short s){
  unsigned u = ((unsigned)(unsigned short)s) << 16;
  float f; __builtin_memcpy(&f, &u, 4); return f;
}
DEVI short f2b(float f){
  __hip_bfloat16 h = __float2bfloat16(f);
  short s; __builtin_memcpy(&s, &h, 2); return s;
}
DEVI float ldflex(const void* p, long i, int bf){
  return bf ? b2f(((const short*)p)[i]) : ((const float*)p)[i];
}
DEVI f32x4 mfma16(short8 a, short8 b, f32x4 c){
  return __builtin_amdgcn_mfma_f32_16x16x32_bf16(a, b, c, 0, 0, 0);
}

// ---------------- ws byte offsets (all 256-aligned) ----------------
constexpr size_t OF_MASKF  = 256;
constexpr size_t OF_INVCNT = 65792;
constexpr size_t OF_XJ     = 69888;
constexpr size_t OF_XW     = 4264192;
constexpr size_t OF_XT     = 4788480;
constexpr size_t OF_W1T    = 5312768;   // bf16 [7][128][256]
constexpr size_t OF_W2T    = 5771520;   // bf16 [7][128][128]
constexpr size_t OF_EB1F   = 6000896;
constexpr size_t OF_EB2F   = 6004480;
constexpr size_t OF_JW1T   = 6008064;   // bf16 [128][512]
constexpr size_t OF_JW2T   = 6139136;   // bf16 [128][128]
constexpr size_t OF_JB1F   = 6171904;
constexpr size_t OF_JB2F   = 6172416;
constexpr size_t OF_WTW1T  = 6172928;   // bf16 [2][128][384]
constexpr size_t OF_WTW2T  = 6369536;   // bf16 [2][128][128]
constexpr size_t OF_WTB1F  = 6435072;
constexpr size_t OF_WTB2F  = 6436096;
constexpr size_t OF_UV     = 6437120;   // bf16 now: 14,680,064 elems = 29.4MB
constexpr size_t OF_POOL   = 65157376;  // bf16, 7,340,032 elems

// projection jobs: job = net*2 + half (half0=src gets bias). 512 rows/wg.
__constant__ long long PJ_OFF[14] = {0,2097152,4194304,6291456,6553600,8650752,
  8912896,9175040,11272192,11534336,11796480,12058624,14155776,14417920};
__constant__ int PJ_SRC[14] = {0,0,0,1,0,2,1,0,1,2,2,0,2,1}; // 0=J,1=W,2=T
__constant__ int PJ_CUM[15] = {0,32,64,96,100,132,136,140,172,176,180,184,216,220,224};
// edge nets, 512 edge-rows per wg
__constant__ int EN_CUM[8]  = {0,512,576,640,704,712,776,784};
__constant__ int EN_LGNS[7] = {4,4,4,1,1,1,1};
__constant__ int EN_LGND[7] = {4,1,1,4,1,4,1};
__constant__ long long EN_POOL[7] = {0,2097152,4194304,6291456,6553600,6815744,7077888};
// transpose jobs
__constant__ int TJ_CUM[21] = {0,32,64,96,128,160,192,224,240,256,272,288,304,320,336,400,416,464,512,528,544};
__constant__ int TJ_SEL[20] = {0,0,0,0,0,0,0,1,1,1,1,1,1,1,2,3,4,4,5,5};
__constant__ int TJ_OFF[20] = {0,32768,65536,98304,131072,163840,196608,
                               0,16384,32768,49152,65536,81920,98304,
                               0,0,0,49152,0,16384};
__constant__ int TJ_R[20]   = {256,256,256,256,256,256,256,128,128,128,128,128,128,128,512,128,384,384,128,128};

// -------- probe: detect float dtype (f32 vs bf16) and mask format --------
__global__ __launch_bounds__(64) void k_probe(const void* jets, const void* mask, int* flags){
  int l = threadIdx.x;
  int extreme = 0;
  #pragma unroll
  for(int s=0;s<4;s++){
    unsigned short v = ((const unsigned short*)jets)[(l*4+s)*2];
    int e = (v>>7)&0xff;
    if(e<110||e>140) extreme++;
  }
  #pragma unroll
  for(int o=1;o<64;o<<=1) extreme += __shfl_xor(extreme, o);
  bool all01=true, allf32=true;
  #pragma unroll
  for(int s=0;s<4;s++){
    unsigned w = ((const unsigned*)mask)[l*4+s];
    if(w>1u) all01=false;
    if(w!=0u && w!=0x3F800000u) allf32=false;
  }
  bool allbfv=true; int evnz=0;
  #pragma unroll
  for(int s=0;s<8;s++){
    unsigned short v = ((const unsigned short*)mask)[l*8+s];
    if(v!=0&&v!=0x3F80) allbfv=false;
    if(((l*8+s)&1)==0 && v!=0) evnz++;
  }
  #pragma unroll
  for(int o=1;o<64;o<<=1) evnz += __shfl_xor(evnz, o);
  bool allb01=true;
  #pragma unroll
  for(int s=0;s<16;s++){ if(((const unsigned char*)mask)[l*16+s]>1) allb01=false; }
  int a01 = __all(all01), af32 = __all(allf32), abf = __all(allbfv), ab01 = __all(allb01);
  if(l==0){
    flags[0] = (extreme <= 32) ? 1 : 0;   // 1=bf16 inputs, 0=f32
    int fmt = 0;
    if(a01) fmt=0; else if(abf && evnz>0) fmt=2; else if(af32) fmt=3; else if(ab01) fmt=1;
    flags[1] = fmt;
  }
}

// -------- maskf + invcnt --------
__global__ __launch_bounds__(256) void k_mask(const void* mask, const int* flags,
                                              float* maskf, float* invcnt){
  int t = blockIdx.x*256 + threadIdx.x;  // 0..16383
  int fmt = flags[1];
  float m;
  if(fmt==0)      m = (((const int*)mask)[t]!=0) ? 1.f : 0.f;
  else if(fmt==1) m = (((const unsigned char*)mask)[t]!=0) ? 1.f : 0.f;
  else if(fmt==2) m = (b2f(((const short*)mask)[t])!=0.f) ? 1.f : 0.f;
  else            m = (((const float*)mask)[t]!=0.f) ? 1.f : 0.f;
  maskf[t] = m;
  float s = m;
  for(int o=1;o<16;o<<=1) s += __shfl_xor(s, o);
  if((t&15)==0) invcnt[t>>4] = 1.f / fmaxf(s, 1.f);
}

// -------- biases to f32 --------
__global__ __launch_bounds__(256) void k_bias(const void* eb1, const void* eb2, const void* jb1,
    const void* jb2, const void* wb1, const void* wb2, const int* flags,
    float* EB1F, float* EB2F, float* JB1F, float* JB2F, float* WTB1F, float* WTB2F){
  int id = blockIdx.x*256 + threadIdx.x;
  int bf = flags[0];
  if(id<896)        EB1F[id]       = ldflex(eb1, id, bf);
  else if(id<1792)  EB2F[id-896]   = ldflex(eb2, id-896, bf);
  else if(id<1920)  JB1F[id-1792]  = ldflex(jb1, id-1792, bf);
  else if(id<2048)  JB2F[id-1920]  = ldflex(jb2, id-1920, bf);
  else if(id<2304)  WTB1F[id-2048] = ldflex(wb1, id-2048, bf);
  else if(id<2560)  WTB2F[id-2304] = ldflex(wb2, id-2304, bf);
}

// -------- convert node inputs to canonical bf16 (x4 vectorized) --------
__global__ __launch_bounds__(256) void k_convx(const void* jets, const void* nw, const void* nt,
                                               const int* flags, short* XJ, short* XW, short* XT){
  long i = ((long)blockIdx.x*256 + threadIdx.x)*4;
  int bf = flags[0];
  const void* src; short* dst; long o;
  if(i < 2097152){ src=jets; dst=XJ; o=i; }
  else if(i < 2359296){ src=nw; dst=XW; o=i-2097152; }
  else { src=nt; dst=XT; o=i-2359296; }
  short4v r;
  if(bf){
    r = *(const short4v*)((const short*)src + o);
  } else {
    f32x4 v = *(const f32x4*)((const float*)src + o);
    #pragma unroll
    for(int e=0;e<4;e++) r[e] = f2b(v[e]);
  }
  *(short4v*)(dst + o) = r;
}

// -------- weight transpose via LDS 32x32 tiles (src [R][128] -> dst [128][R]) --------
__global__ __launch_bounds__(256) void k_trans(const void* eW1, const void* eW2, const void* jW1,
    const void* jW2, const void* wW1, const void* wW2, const int* flags,
    short* W1T, short* W2T, short* JW1T, short* JW2T, short* WTW1T, short* WTW2T){
  __shared__ float tl[32][33];
  int tile = blockIdx.x; int job = 0;
  while(tile >= TJ_CUM[job+1]) job++;
  tile -= TJ_CUM[job];
  int sel = TJ_SEL[job]; long off = TJ_OFF[job]; int R = TJ_R[job];
  int bf = flags[0];
  const void* src = sel==0?eW1: sel==1?eW2: sel==2?jW1: sel==3?jW2: sel==4?wW1: wW2;
  short* dst = sel==0?W1T: sel==1?W2T: sel==2?JW1T: sel==3?JW2T: sel==4?WTW1T: WTW2T;
  int tr = (tile>>2)*32, tc = (tile&3)*32;
  int t = threadIdx.x, r = t>>3, c4 = (t&7)*4;
  #pragma unroll
  for(int j=0;j<4;j++) tl[r][c4+j] = ldflex(src, off + (long)(tr+r)*128 + tc + c4 + j, bf);
  __syncthreads();
  short4v o;
  #pragma unroll
  for(int j=0;j<4;j++) o[j] = f2b(tl[c4+j][r]);
  *(short4v*)(dst + off + (long)(tc+r)*R + tr + c4) = o;
}

// -------- projections: UVb[row][128] bf16 = X @ W1half (+b1 on src half) --------
// 512 threads = 8 waves; wave = 16 rows x 64 cols; 8 chunks of 64 rows.
// Barrier-free; B-frags in registers; compiler can pipeline chunk loads.
__global__ __launch_bounds__(512) void k_proj(const short* XJ, const short* XW, const short* XT,
                                              const short* W1T, const float* EB1F, short* UVb){
  int bid = blockIdx.x;
  int job = 0;
  while(bid >= PJ_CUM[job+1]) job++;
  long row0 = (long)(bid - PJ_CUM[job]) * 512;
  const short* X = (PJ_SRC[job]==0) ? XJ : ((PJ_SRC[job]==1) ? XW : XT);
  const short* Wb = W1T + (long)(job>>1)*32768 + (job&1)*128;  // rows stride 256
  short* out = UVb + PJ_OFF[job];
  int net = job>>1; bool addb = (job&1)==0;
  int t = threadIdx.x, lane = t & 63, wv = t >> 6;
  int rb = wv >> 1, ch = (wv & 1)*64;
  int cl = lane & 15, kh = lane >> 4;
  short8 b[4][4];
  float bias[4];
  #pragma unroll
  for(int nt=0;nt<4;nt++){
    #pragma unroll
    for(int ks=0;ks<4;ks++)
      b[nt][ks] = *(const short8*)(Wb + (ch + nt*16 + cl)*256 + ks*32 + kh*8);
    bias[nt] = addb ? EB1F[net*128 + ch + nt*16 + cl] : 0.f;
  }
  for(int c=0;c<8;c++){
    long T0 = row0 + c*64 + rb*16;
    long R = T0 + cl;
    short8 a[4];
    #pragma unroll
    for(int ks=0;ks<4;ks++)
      a[ks] = *(const short8*)(X + R*128 + ks*32 + kh*8);
    f32x4 acc[4] = {};
    #pragma unroll
    for(int ks=0;ks<4;ks++)
      #pragma unroll
      for(int nt=0;nt<4;nt++)
        acc[nt] = mfma16(a[ks], b[nt][ks], acc[nt]);
    #pragma unroll
    for(int nt=0;nt<4;nt++){
      int col = ch + nt*16 + cl;
      #pragma unroll
      for(int r=0;r<4;r++)
        out[(T0 + kh*4 + r)*128 + col] = f2b(acc[nt][r] + bias[nt]);
    }
  }
}

// -------- edge layer2 + pooling: barrier-free, W2 frags in regs --------
// 512 threads = 8 waves; wave = 16 rows x 64 cols; 8 chunks of 64 rows; 512 rows/wg.
__global__ __launch_bounds__(512) void k_edge(const short* UVb, const short* W2T, const float* EB2F,
                                              const float* maskf, const float* invcnt, short* POOL){
  int bid = blockIdx.x;
  int net = 0;
  while(bid >= EN_CUM[net+1]) net++;
  int idx = bid - EN_CUM[net];
  int lgNs = EN_LGNS[net], lgNd = EN_LGND[net];
  int masked = (lgNd == 4);
  long R0 = (long)idx * 512;
  const short* U = UVb + PJ_OFF[2*net];
  const short* V = UVb + PJ_OFF[2*net+1];
  const short* Wb = W2T + (long)net*16384;
  short* pool = POOL + EN_POOL[net];
  int t = threadIdx.x, lane = t & 63, wv = t >> 6;
  int rb = wv >> 1, ch = (wv & 1)*64;
  int cl = lane & 15, kh = lane >> 4;
  short8 b[4][4];
  float bias[4];
  #pragma unroll
  for(int nt=0;nt<4;nt++){
    #pragma unroll
    for(int ks=0;ks<4;ks++)
      b[nt][ks] = *(const short8*)(Wb + (ch + nt*16 + cl)*128 + ks*32 + kh*8);
    bias[nt] = EB2F[net*128 + ch + nt*16 + cl];
  }
  for(int c=0;c<8;c++){
    long T0 = R0 + c*64 + rb*16;
    long R = T0 + cl;
    long urow = R >> lgNd;
    long vrow = ((R >> (lgNs+lgNd)) << lgNd) | (R & ((1<<lgNd)-1));
    short8 u[4], v[4], a[4];
    #pragma unroll
    for(int ks=0;ks<4;ks++)
      u[ks] = *(const short8*)(U + urow*128 + ks*32 + kh*8);
    #pragma unroll
    for(int ks=0;ks<4;ks++)
      v[ks] = *(const short8*)(V + vrow*128 + ks*32 + kh*8);
    #pragma unroll
    for(int ks=0;ks<4;ks++)
      #pragma unroll
      for(int e=0;e<8;e++)
        a[ks][e] = f2b(fmaxf(b2f(u[ks][e]) + b2f(v[ks][e]), 0.f));
    f32x4 acc[4] = {};
    #pragma unroll
    for(int ks=0;ks<4;ks++)
      #pragma unroll
      for(int nt=0;nt<4;nt++)
        acc[nt] = mfma16(a[ks], b[nt][ks], acc[nt]);
    // epilogue: bias + relu + pool
    if(masked){
      long bb = T0 >> (lgNs + 4);
      float wr[4];
      #pragma unroll
      for(int r=0;r<4;r++)
        wr[r] = maskf[bb*16 + ((T0 + kh*4 + r) & 15)] * invcnt[bb];
      #pragma unroll
      for(int nt=0;nt<4;nt++){
        int col = ch + nt*16 + cl;
        float s = fmaxf(acc[nt][0]+bias[nt],0.f)*wr[0]
                + fmaxf(acc[nt][1]+bias[nt],0.f)*wr[1]
                + fmaxf(acc[nt][2]+bias[nt],0.f)*wr[2]
                + fmaxf(acc[nt][3]+bias[nt],0.f)*wr[3];
        s += __shfl_xor(s, 16);
        s += __shfl_xor(s, 32);
        if(lane < 16)
          pool[(T0 >> 4)*128 + col] = f2b(s);
      }
    } else {
      #pragma unroll
      for(int nt=0;nt<4;nt++){
        int col = ch + nt*16 + cl;
        float v0 = fmaxf(acc[nt][0]+bias[nt],0.f);
        float v1 = fmaxf(acc[nt][1]+bias[nt],0.f);
        float v2 = fmaxf(acc[nt][2]+bias[nt],0.f);
        float v3 = fmaxf(acc[nt][3]+bias[nt],0.f);
        long g = (T0 + kh*4) >> 1;
        pool[g*128 + col]     = f2b((v0+v1)*0.5f);
        pool[(g+1)*128 + col] = f2b((v2+v3)*0.5f);
      }
    }
  }
}

// -------- node nets: 64 rows/wg (4 waves x 16 rows), h1 in LDS --------
__global__ __launch_bounds__(256) void k_node(const short* XJ, const short* XW, const short* XT,
    const short* POOL, const short* JW1T, const short* JW2T, const float* JB1F, const float* JB2F,
    const short* WTW1T, const short* WTW2T, const float* WTB1F, const float* WTB2F,
    const float* maskf, const int* flags, void* out){
  __shared__ short hs[8192];  // 64 x 128 bf16, XOR-swizzled
  int bid = blockIdx.x;
  int net; long row0;
  if(bid < 256){ net=0; row0=(long)bid*64; }
  else if(bid < 288){ net=1; row0=(long)(bid-256)*64; }
  else { net=2; row0=(long)(bid-288)*64; }
  int K1 = (net==0) ? 512 : 384;
  const short* X = (net==0) ? XJ : ((net==1) ? XW : XT);
  const short *PA, *PB, *PC = nullptr;
  if(net==0){ PA=POOL; PB=POOL+2097152; PC=POOL+4194304; }
  else if(net==1){ PA=POOL+6291456; PB=POOL+6553600; }
  else { PA=POOL+6815744; PB=POOL+7077888; }
  const short* W1 = (net==0) ? JW1T : WTW1T + (long)(net-1)*49152;
  const short* W2 = (net==0) ? JW2T : WTW2T + (long)(net-1)*16384;
  const float* B1 = (net==0) ? JB1F : WTB1F + (net-1)*128;
  const float* B2 = (net==0) ? JB2F : WTB2F + (net-1)*128;
  int t = threadIdx.x;
  int lane = t & 63, wv = t >> 6;
  int cl = lane & 15, kh = lane >> 4;
  f32x4 acc[8] = {};
  for(int ks=0; ks<K1/32; ks++){
    int kk = ks*32 + kh*8;
    int sel = kk >> 7, ko = kk & 127;   // wave-uniform per ks
    const short* SA = (sel==0) ? X : ((sel==1) ? PA : ((sel==2) ? PB : PC));
    short8 a = *(const short8*)(SA + (row0 + wv*16 + cl)*128 + ko);
    short8 b[8];
    #pragma unroll
    for(int nt=0;nt<8;nt++)
      b[nt] = *(const short8*)(W1 + (long)(nt*16 + cl)*K1 + ks*32 + kh*8);
    #pragma unroll
    for(int nt=0;nt<8;nt++)
      acc[nt] = mfma16(a, b[nt], acc[nt]);
  }
  #pragma unroll
  for(int nt=0;nt<8;nt++){
    int col = nt*16 + cl;
    float bias = B1[col];
    #pragma unroll
    for(int r=0;r<4;r++){
      int rl = wv*16 + kh*4 + r;
      float v = fmaxf(acc[nt][r] + bias, 0.f);
      *(short*)((char*)hs + ((rl*256 + col*2) ^ ((rl&7)<<4))) = f2b(v);
    }
  }
  __syncthreads();
  f32x4 acc2[8] = {};
  for(int k0=0;k0<128;k0+=32){
    int rr = wv*16 + cl;
    short8 a = *(const short8*)((const char*)hs + ((rr*256 + (k0 + kh*8)*2) ^ ((rr&7)<<4)));
    short8 b[8];
    #pragma unroll
    for(int nt=0;nt<8;nt++)
      b[nt] = *(const short8*)(W2 + (nt*16 + cl)*128 + k0 + kh*8);
    #pragma unroll
    for(int nt=0;nt<8;nt++)
      acc2[nt] = mfma16(a, b[nt], acc2[nt]);
  }
  int obf = flags[0];
  #pragma unroll
  for(int nt=0;nt<8;nt++){
    int col = nt*16 + cl;
    float bias = B2[col];
    #pragma unroll
    for(int r=0;r<4;r++){
      int rl = wv*16 + kh*4 + r;
      long grow = row0 + rl;
      float v = fmaxf(acc2[nt][r] + bias, 0.f);
      long bb, node;
      if(net==0){ bb = grow>>4; node = grow&15; v *= maskf[grow]; }
      else if(net==1){ bb = grow>>1; node = 16 + (grow&1); }
      else { bb = grow>>1; node = 18 + (grow&1); }
      long oi = (bb*20 + node)*128 + col;
      if(obf) ((__hip_bfloat16*)out)[oi] = __float2bfloat16(v);
      else    ((float*)out)[oi] = v;
    }
  }
}

extern "C" void kernel_launch(void* const* d_in, const int* in_sizes, int n_in,
                              void* d_out, int out_size, void* d_ws, size_t ws_size,
                              hipStream_t stream){
  char* ws = (char*)d_ws;
  int*   flags  = (int*)ws;
  float* maskf  = (float*)(ws + OF_MASKF);
  float* invcnt = (float*)(ws + OF_INVCNT);
  short* XJ     = (short*)(ws + OF_XJ);
  short* XW     = (short*)(ws + OF_XW);
  short* XT     = (short*)(ws + OF_XT);
  short* W1T    = (short*)(ws + OF_W1T);
  short* W2T    = (short*)(ws + OF_W2T);
  float* EB1F   = (float*)(ws + OF_EB1F);
  float* EB2F   = (float*)(ws + OF_EB2F);
  short* JW1T   = (short*)(ws + OF_JW1T);
  short* JW2T   = (short*)(ws + OF_JW2T);
  float* JB1F   = (float*)(ws + OF_JB1F);
  float* JB2F   = (float*)(ws + OF_JB2F);
  short* WTW1T  = (short*)(ws + OF_WTW1T);
  short* WTW2T  = (short*)(ws + OF_WTW2T);
  float* WTB1F  = (float*)(ws + OF_WTB1F);
  float* WTB2F  = (float*)(ws + OF_WTB2F);
  short* UVb    = (short*)(ws + OF_UV);
  short* POOL   = (short*)(ws + OF_POOL);

  k_probe<<<1, 64, 0, stream>>>(d_in[0], d_in[3], flags);
  k_mask <<<64, 256, 0, stream>>>(d_in[3], flags, maskf, invcnt);
  k_bias <<<10, 256, 0, stream>>>(d_in[5], d_in[7], d_in[9], d_in[11], d_in[13], d_in[15],
                                  flags, EB1F, EB2F, JB1F, JB2F, WTB1F, WTB2F);
  k_convx<<<2560, 256, 0, stream>>>(d_in[0], d_in[1], d_in[2], flags, XJ, XW, XT);
  k_trans<<<544, 256, 0, stream>>>(d_in[4], d_in[6], d_in[8], d_in[10], d_in[12], d_in[14],
                                   flags, W1T, W2T, JW1T, JW2T, WTW1T, WTW2T);
  k_proj <<<224, 512, 0, stream>>>(XJ, XW, XT, W1T, EB1F, UVb);
  k_edge <<<784, 512, 0, stream>>>(UVb, W2T, EB2F, maskf, invcnt, POOL);
  k_node <<<320, 256, 0, stream>>>(XJ, XW, XT, POOL, JW1T, JW2T, JB1F, JB2F,
                                   WTW1T, WTW2T, WTB1F, WTB2F, maskf, flags, d_out);
}